// Round 1
// baseline (479.150 us; speedup 1.0000x reference)
//
#include <hip/hip_runtime.h>

typedef __bf16 bf16_t;
typedef __bf16 bf16x8 __attribute__((ext_vector_type(8)));
typedef float f32x4 __attribute__((ext_vector_type(4)));

#define MPAD  8256   // 32*257 = 8224 padded to 129*64
#define NNODE 257
#define NB    32

// ---------------- prep: transpose + f32->bf16 ----------------
// fmap [B, 2048, 256] f32 -> X [MPAD, 2048] bf16, row r = b*257+n (n<256; rest pre-zeroed)
__global__ __launch_bounds__(256) void prep_x_kernel(const float* __restrict__ fmap,
                                                     bf16_t* __restrict__ X) {
    __shared__ float tile[32][33];
    int c0 = blockIdx.x * 32, n0 = blockIdx.y * 32, b = blockIdx.z;
    int tx = threadIdx.x, ty = threadIdx.y;
    const float* f = fmap + (size_t)b * 2048 * 256;
#pragma unroll
    for (int i = 0; i < 4; i++) {
        int c = c0 + ty + i * 8;
        tile[ty + i * 8][tx] = f[(size_t)c * 256 + n0 + tx];
    }
    __syncthreads();
    bf16_t* Xr = X + (size_t)(b * 257 + n0) * 2048 + c0;
#pragma unroll
    for (int i = 0; i < 4; i++) {
        int n = ty + i * 8;
        Xr[(size_t)n * 2048 + tx] = (bf16_t)tile[tx][n];
    }
}

// W [K, N] f32 -> Wt [N, K] bf16
__global__ __launch_bounds__(256) void prep_w_kernel(const float* __restrict__ W,
                                                     bf16_t* __restrict__ Wt,
                                                     int K, int N) {
    __shared__ float tile[32][33];
    int k0 = blockIdx.x * 32, n0 = blockIdx.y * 32;
    int tx = threadIdx.x, ty = threadIdx.y;
#pragma unroll
    for (int i = 0; i < 4; i++)
        tile[ty + i * 8][tx] = W[(size_t)(k0 + ty + i * 8) * N + n0 + tx];
    __syncthreads();
#pragma unroll
    for (int i = 0; i < 4; i++)
        Wt[(size_t)(n0 + ty + i * 8) * K + k0 + tx] = (bf16_t)tile[tx][ty + i * 8];
}

// ---------------- CSR by dst (single block) ----------------
__global__ void build_csr_kernel(const int* __restrict__ dstv, int E,
                                 int* __restrict__ indptr, int* __restrict__ eidx) {
    __shared__ int cnt[258];
    __shared__ int off[258];
    int t = threadIdx.x;
    for (int i = t; i < 258; i += 256) cnt[i] = 0;
    __syncthreads();
    for (int e = t; e < E; e += 256) atomicAdd(&cnt[dstv[e] + 1], 1);
    __syncthreads();
    if (t == 0) {
        int s = 0;
        for (int i = 0; i < 258; i++) { s += cnt[i]; off[i] = s; }
    }
    __syncthreads();
    for (int i = t; i < 258; i += 256) indptr[i] = off[i];
    __syncthreads();
    for (int e = t; e < E; e += 256) {
        int p = atomicAdd(&off[dstv[e]], 1);
        eidx[p] = e;
    }
}

// ---------------- bf16 MFMA GEMM: C[M,N] = A[M,K] * Bt[N,K]^T ----------------
#define LDT 40  // LDS row stride in bf16 (80B): 8-row bank period -> 2-way (free)
__global__ __launch_bounds__(256) void gemm_kernel(const bf16_t* __restrict__ A,
                                                   const bf16_t* __restrict__ Bt,
                                                   float* __restrict__ C,
                                                   int K, int N) {
    __shared__ bf16_t As[64 * LDT];
    __shared__ bf16_t Bs[64 * LDT];
    int row0 = blockIdx.y * 64, col0 = blockIdx.x * 64;
    int t = threadIdx.x;
    int wave = t >> 6, lane = t & 63;
    int lr = t >> 2, lc = (t & 3) * 8;       // staging: thread loads 8 bf16 of row lr
    const bf16_t* Ap = A + (size_t)(row0 + lr) * K + lc;
    const bf16_t* Bp = Bt + (size_t)(col0 + lr) * K + lc;
    f32x4 acc[4] = {};
    int arow = wave * 16 + (lane & 15);
    int kq = (lane >> 4) * 8;
    for (int k0 = 0; k0 < K; k0 += 32) {
        *(bf16x8*)&As[lr * LDT + lc] = *(const bf16x8*)(Ap + k0);
        *(bf16x8*)&Bs[lr * LDT + lc] = *(const bf16x8*)(Bp + k0);
        __syncthreads();
        bf16x8 af = *(const bf16x8*)&As[arow * LDT + kq];
#pragma unroll
        for (int ct = 0; ct < 4; ct++) {
            bf16x8 bfr = *(const bf16x8*)&Bs[(ct * 16 + (lane & 15)) * LDT + kq];
            acc[ct] = __builtin_amdgcn_mfma_f32_16x16x32_bf16(af, bfr, acc[ct], 0, 0, 0);
        }
        __syncthreads();
    }
    // C/D layout: col = lane&15, row = (lane>>4)*4 + reg
    int crow = row0 + wave * 16 + (lane >> 4) * 4;
    int ccol = col0 + (lane & 15);
#pragma unroll
    for (int ct = 0; ct < 4; ct++)
#pragma unroll
        for (int r = 0; r < 4; r++)
            C[(size_t)(crow + r) * N + ccol + ct * 16] = acc[ct][r];
}

// ---------------- es/ed per-row head dots ----------------
// Hmat [.., 4*D]; es/ed [.., 4]; one block per real row, wave h handles head h
__global__ __launch_bounds__(256) void esed_kernel(const float* __restrict__ Hmat,
                                                   const float* __restrict__ a_s,
                                                   const float* __restrict__ a_d,
                                                   float* __restrict__ es,
                                                   float* __restrict__ ed, int D) {
    int r = blockIdx.x;
    int h = threadIdx.x >> 6, lane = threadIdx.x & 63;
    const float* row = Hmat + (size_t)r * 4 * D + h * D;
    float ss = 0.f, sd = 0.f;
    for (int d = lane; d < D; d += 64) {
        float v = row[d];
        ss += v * a_s[h * D + d];
        sd += v * a_d[h * D + d];
    }
#pragma unroll
    for (int o = 32; o > 0; o >>= 1) {
        ss += __shfl_down(ss, o);
        sd += __shfl_down(sd, o);
    }
    if (lane == 0) { es[r * 4 + h] = ss; ed[r * 4 + h] = sd; }
}

// ---------------- edge softmax + aggregate (one block per (node, graph)) ----------------
__global__ __launch_bounds__(256) void attn_kernel(const float* __restrict__ Hmat,
                                                   const float* __restrict__ es,
                                                   const float* __restrict__ ed,
                                                   const int* __restrict__ indptr,
                                                   const int* __restrict__ eidx,
                                                   const int* __restrict__ srcv,
                                                   const float* __restrict__ bias,
                                                   float* __restrict__ outf,
                                                   bf16_t* __restrict__ outb,
                                                   int D) {
    int d = blockIdx.x, b = blockIdx.y;
    int r = b * 257 + d;
    int t = threadIdx.x;
    int e0 = indptr[d];
    int deg = indptr[d + 1] - e0;
    __shared__ float alpha[NNODE * 4];
    __shared__ float red[256];
    __shared__ float mh[4], dh[4];
    float lmax[4] = {-1e30f, -1e30f, -1e30f, -1e30f};
    for (int i = t; i < deg; i += 256) {
        int s = srcv[eidx[e0 + i]];
        int rs = (b * 257 + s) * 4;
#pragma unroll
        for (int h = 0; h < 4; h++) {
            float v = es[rs + h] + ed[r * 4 + h];
            v = v > 0.f ? v : 0.2f * v;   // leaky_relu 0.2 (before softmax)
            alpha[i * 4 + h] = v;
            lmax[h] = fmaxf(lmax[h], v);
        }
    }
#pragma unroll
    for (int h = 0; h < 4; h++) {
        red[t] = lmax[h];
        __syncthreads();
        for (int s2 = 128; s2 > 0; s2 >>= 1) {
            if (t < s2) red[t] = fmaxf(red[t], red[t + s2]);
            __syncthreads();
        }
        if (t == 0) mh[h] = red[0];
        __syncthreads();
    }
    float lsum[4] = {0.f, 0.f, 0.f, 0.f};
    for (int i = t; i < deg; i += 256) {
#pragma unroll
        for (int h = 0; h < 4; h++) {
            float a = __expf(alpha[i * 4 + h] - mh[h]);
            alpha[i * 4 + h] = a;
            lsum[h] += a;
        }
    }
#pragma unroll
    for (int h = 0; h < 4; h++) {
        red[t] = lsum[h];
        __syncthreads();
        for (int s2 = 128; s2 > 0; s2 >>= 1) {
            if (t < s2) red[t] += red[t + s2];
            __syncthreads();
        }
        if (t == 0) dh[h] = red[0];
        __syncthreads();
    }
    if (t < D) {
        float acc[4] = {0.f, 0.f, 0.f, 0.f};
        for (int i = 0; i < deg; i++) {
            int s = srcv[eidx[e0 + i]];
            const float* hrow = Hmat + (size_t)(b * 257 + s) * 4 * D;
#pragma unroll
            for (int h = 0; h < 4; h++)
                acc[h] += alpha[i * 4 + h] * hrow[h * D + t];
        }
        float o = 0.f;
#pragma unroll
        for (int h = 0; h < 4; h++) o += acc[h] / (dh[h] + 1e-16f);
        o = o * 0.25f + bias[t];
        if (outb) outb[(size_t)r * D + t] = (bf16_t)o;
        else      outf[(size_t)r * D + t] = o;
    }
}

// ---------------- per-graph head: pool weights, weighted mean, MLP ----------------
__global__ __launch_bounds__(256) void head_kernel(const float* __restrict__ out2,
                                                   const float* __restrict__ Wp,
                                                   const float* __restrict__ bp,
                                                   const float* __restrict__ Wc1,
                                                   const float* __restrict__ bc1,
                                                   const float* __restrict__ Wc2,
                                                   const float* __restrict__ bc2,
                                                   float* __restrict__ outp) {
    int b = blockIdx.x, t = threadIdx.x;
    __shared__ float wsh[NNODE];
    __shared__ float gsh[128];
    __shared__ float h1[64];
    const float* X = out2 + (size_t)b * 257 * 128;
    for (int n = t; n < 257; n += 256) {
        float s = bp[0];
        for (int k = 0; k < 128; k++) s += X[n * 128 + k] * Wp[k];
        float wv = 1.f / (1.f + expf(-s));
        wsh[n] = wv;
        outp[32 + b * 257 + n] = wv;   // atts output
    }
    __syncthreads();
    if (t < 128) {
        float s = 0.f;
        for (int n = 0; n < 257; n++) s += X[n * 128 + t] * wsh[n];
        gsh[t] = s * (1.f / 257.f);    // global_mean_pool of x*w
    }
    __syncthreads();
    if (t < 64) {
        float s = bc1[t];
        for (int k = 0; k < 128; k++) s += gsh[k] * Wc1[k * 64 + t];
        h1[t] = fmaxf(s, 0.f);
    }
    __syncthreads();
    if (t == 0) {
        float s = bc2[0];
        for (int j = 0; j < 64; j++) s += h1[j] * Wc2[j];
        outp[b] = 1.f / (1.f + expf(-s));   // preds output
    }
}

// ---------------- launch ----------------
extern "C" void kernel_launch(void* const* d_in, const int* in_sizes, int n_in,
                              void* d_out, int out_size, void* d_ws, size_t ws_size,
                              hipStream_t stream) {
    const float* fmap   = (const float*)d_in[0];
    const float* W1     = (const float*)d_in[1];
    const float* a_src1 = (const float*)d_in[2];
    const float* a_dst1 = (const float*)d_in[3];
    const float* b1     = (const float*)d_in[4];
    const float* W2     = (const float*)d_in[5];
    const float* a_src2 = (const float*)d_in[6];
    const float* a_dst2 = (const float*)d_in[7];
    const float* b2     = (const float*)d_in[8];
    const float* Wp     = (const float*)d_in[9];
    const float* bp     = (const float*)d_in[10];
    const float* Wc1    = (const float*)d_in[11];
    const float* bc1    = (const float*)d_in[12];
    const float* Wc2    = (const float*)d_in[13];
    const float* bc2    = (const float*)d_in[14];
    const int*   srcv   = (const int*)d_in[15];
    const int*   dstv   = (const int*)d_in[16];
    int E = in_sizes[15];
    float* outp = (float*)d_out;

    char* w = (char*)d_ws;
    size_t off = 0;
    auto alloc = [&](size_t bytes) -> void* {
        void* p = w + off;
        off += (bytes + 255) & ~(size_t)255;
        return p;
    };
    bf16_t* X    = (bf16_t*)alloc((size_t)MPAD * 2048 * sizeof(bf16_t));
    bf16_t* W1t  = (bf16_t*)alloc((size_t)1024 * 2048 * sizeof(bf16_t));
    bf16_t* W2t  = (bf16_t*)alloc((size_t)512 * 256 * sizeof(bf16_t));
    float*  H1   = (float*)alloc((size_t)MPAD * 1024 * sizeof(float));
    float*  es1  = (float*)alloc((size_t)MPAD * 4 * sizeof(float));
    float*  ed1  = (float*)alloc((size_t)MPAD * 4 * sizeof(float));
    bf16_t* out1 = (bf16_t*)alloc((size_t)MPAD * 256 * sizeof(bf16_t));
    float*  H2   = (float*)alloc((size_t)MPAD * 512 * sizeof(float));
    float*  es2  = (float*)alloc((size_t)MPAD * 4 * sizeof(float));
    float*  ed2  = (float*)alloc((size_t)MPAD * 4 * sizeof(float));
    float*  out2 = (float*)alloc((size_t)MPAD * 128 * sizeof(float));
    int*  indptr = (int*)alloc(258 * sizeof(int));
    int*  eidx   = (int*)alloc((size_t)E * sizeof(int));

    // zero X: covers disease-node rows (n==256) and pad rows 8224..8255
    hipMemsetAsync(X, 0, (size_t)MPAD * 2048 * sizeof(bf16_t), stream);

    prep_w_kernel<<<dim3(64, 32), dim3(32, 8), 0, stream>>>(W1, W1t, 2048, 1024);
    prep_w_kernel<<<dim3(8, 16), dim3(32, 8), 0, stream>>>(W2, W2t, 256, 512);
    prep_x_kernel<<<dim3(64, 8, NB), dim3(32, 8), 0, stream>>>(fmap, X);
    build_csr_kernel<<<1, 256, 0, stream>>>(dstv, E, indptr, eidx);

    // layer 1
    gemm_kernel<<<dim3(1024 / 64, MPAD / 64), 256, 0, stream>>>(X, W1t, H1, 2048, 1024);
    esed_kernel<<<NB * NNODE, 256, 0, stream>>>(H1, a_src1, a_dst1, es1, ed1, 256);
    attn_kernel<<<dim3(NNODE, NB), 256, 0, stream>>>(H1, es1, ed1, indptr, eidx, srcv,
                                                     b1, nullptr, out1, 256);
    // layer 2
    gemm_kernel<<<dim3(512 / 64, MPAD / 64), 256, 0, stream>>>(out1, W2t, H2, 256, 512);
    esed_kernel<<<NB * NNODE, 256, 0, stream>>>(H2, a_src2, a_dst2, es2, ed2, 128);
    attn_kernel<<<dim3(NNODE, NB), 256, 0, stream>>>(H2, es2, ed2, indptr, eidx, srcv,
                                                     b2, out2, nullptr, 128);
    // head
    head_kernel<<<NB, 256, 0, stream>>>(out2, Wp, bp, Wc1, bc1, Wc2, bc2, outp);

    (void)n_in; (void)out_size; (void)ws_size;
}

// Round 2
// 419.315 us; speedup vs baseline: 1.1427x; 1.1427x over previous
//
#include <hip/hip_runtime.h>

typedef __bf16 bf16_t;
typedef __bf16 bf16x8 __attribute__((ext_vector_type(8)));
typedef float f32x4 __attribute__((ext_vector_type(4)));

#define MPAD  8320   // 32*257 = 8224 padded to 65*128
#define NNODE 257
#define NB    32

__device__ __forceinline__ void gld_lds16(const bf16_t* g, bf16_t* l) {
    // dest = wave-uniform LDS base + lane*16 (hardware); pass lane0 base in l
    __builtin_amdgcn_global_load_lds(
        (const __attribute__((address_space(1))) void*)g,
        (__attribute__((address_space(3))) void*)l, 16, 0, 0);
}

// ---------------- prep: transpose + f32->bf16 ----------------
// fmap [B, 2048, 256] f32 -> X [MPAD, 2048] bf16, row r = b*257+n (n<256; rest pre-zeroed)
__global__ __launch_bounds__(256) void prep_x_kernel(const float* __restrict__ fmap,
                                                     bf16_t* __restrict__ X) {
    __shared__ float tile[32][33];
    int c0 = blockIdx.x * 32, n0 = blockIdx.y * 32, b = blockIdx.z;
    int tx = threadIdx.x, ty = threadIdx.y;
    const float* f = fmap + (size_t)b * 2048 * 256;
#pragma unroll
    for (int i = 0; i < 4; i++) {
        int c = c0 + ty + i * 8;
        tile[ty + i * 8][tx] = f[(size_t)c * 256 + n0 + tx];
    }
    __syncthreads();
    bf16_t* Xr = X + (size_t)(b * 257 + n0) * 2048 + c0;
#pragma unroll
    for (int i = 0; i < 4; i++) {
        int n = ty + i * 8;
        Xr[(size_t)n * 2048 + tx] = (bf16_t)tile[tx][n];
    }
}

// W [K, N] f32 -> Wt [N, K] bf16
__global__ __launch_bounds__(256) void prep_w_kernel(const float* __restrict__ W,
                                                     bf16_t* __restrict__ Wt,
                                                     int K, int N) {
    __shared__ float tile[32][33];
    int k0 = blockIdx.x * 32, n0 = blockIdx.y * 32;
    int tx = threadIdx.x, ty = threadIdx.y;
#pragma unroll
    for (int i = 0; i < 4; i++)
        tile[ty + i * 8][tx] = W[(size_t)(k0 + ty + i * 8) * N + n0 + tx];
    __syncthreads();
#pragma unroll
    for (int i = 0; i < 4; i++)
        Wt[(size_t)(n0 + ty + i * 8) * K + k0 + tx] = (bf16_t)tile[tx][ty + i * 8];
}

// ---------------- CSR by dst (single block) ----------------
__global__ void build_csr_kernel(const int* __restrict__ dstv, int E,
                                 int* __restrict__ indptr, int* __restrict__ eidx) {
    __shared__ int cnt[258];
    __shared__ int off[258];
    int t = threadIdx.x;
    for (int i = t; i < 258; i += 256) cnt[i] = 0;
    __syncthreads();
    for (int e = t; e < E; e += 256) atomicAdd(&cnt[dstv[e] + 1], 1);
    __syncthreads();
    if (t == 0) {
        int s = 0;
        for (int i = 0; i < 258; i++) { s += cnt[i]; off[i] = s; }
    }
    __syncthreads();
    for (int i = t; i < 258; i += 256) indptr[i] = off[i];
    __syncthreads();
    for (int e = t; e < E; e += 256) {
        int p = atomicAdd(&off[dstv[e]], 1);
        eidx[p] = e;
    }
}

// ---------------- m97-style bf16 MFMA GEMM: C[M,N] = A[M,K] * Bt[N,K]^T ----------------
// 128x128 tile, BK=32, 4 waves, 4x4 16x16x32 MFMA per wave, global_load_lds width=16.
// LDS un-padded (global_load_lds lane mapping requires contiguous rows).
__global__ __launch_bounds__(256) void gemm_kernel(const bf16_t* __restrict__ A,
                                                   const bf16_t* __restrict__ Bt,
                                                   float* __restrict__ C,
                                                   int K, int N) {
    __shared__ __align__(16) bf16_t As[128 * 32];
    __shared__ __align__(16) bf16_t Bs[128 * 32];
    int row0 = blockIdx.y * 128, col0 = blockIdx.x * 128;
    int t = threadIdx.x;
    int wave = t >> 6, lane = t & 63;
    int wr = wave >> 1, wc = wave & 1;          // wave covers 64x64 quadrant
    // staging: wave handles chunks {2*wave, 2*wave+1} of A and B (16 rows x 32 cols each)
    int ch0 = wave * 2;
    int srow = (lane >> 2);                     // 0..15 within chunk
    int scol = (lane & 3) * 8;                  // bf16 element offset
    const bf16_t* Abase = A + (size_t)row0 * K;
    const bf16_t* Bbase = Bt + (size_t)col0 * K;
    f32x4 acc[4][4] = {};
    int fr = lane & 15;                         // fragment row/col within 16
    int kq = (lane >> 4) * 8;                   // k-quad offset
    for (int k0 = 0; k0 < K; k0 += 32) {
#pragma unroll
        for (int c = 0; c < 2; c++) {
            int chunk = ch0 + c;
            int row = chunk * 16 + srow;
            gld_lds16(Abase + (size_t)row * K + k0 + scol, &As[chunk * 512]);
            gld_lds16(Bbase + (size_t)row * K + k0 + scol, &Bs[chunk * 512]);
        }
        __syncthreads();   // drains vmcnt(0): global_load_lds complete
        bf16x8 af[4], bf[4];
#pragma unroll
        for (int mr = 0; mr < 4; mr++)
            af[mr] = *(const bf16x8*)&As[(wr * 64 + mr * 16 + fr) * 32 + kq];
#pragma unroll
        for (int nc = 0; nc < 4; nc++)
            bf[nc] = *(const bf16x8*)&Bs[(wc * 64 + nc * 16 + fr) * 32 + kq];
#pragma unroll
        for (int mr = 0; mr < 4; mr++)
#pragma unroll
            for (int nc = 0; nc < 4; nc++)
                acc[mr][nc] = __builtin_amdgcn_mfma_f32_16x16x32_bf16(
                    af[mr], bf[nc], acc[mr][nc], 0, 0, 0);
        __syncthreads();   // LDS consumed; safe to overwrite next iter
    }
    // C/D layout: col = lane&15, row = (lane>>4)*4 + reg
#pragma unroll
    for (int mr = 0; mr < 4; mr++) {
        int crow = row0 + wr * 64 + mr * 16 + (lane >> 4) * 4;
#pragma unroll
        for (int nc = 0; nc < 4; nc++) {
            int ccol = col0 + wc * 64 + nc * 16 + (lane & 15);
#pragma unroll
            for (int r = 0; r < 4; r++)
                C[(size_t)(crow + r) * N + ccol] = acc[mr][nc][r];
        }
    }
}

// ---------------- es/ed per-row head dots ----------------
__global__ __launch_bounds__(256) void esed_kernel(const float* __restrict__ Hmat,
                                                   const float* __restrict__ a_s,
                                                   const float* __restrict__ a_d,
                                                   float* __restrict__ es,
                                                   float* __restrict__ ed, int D) {
    int r = blockIdx.x;
    int h = threadIdx.x >> 6, lane = threadIdx.x & 63;
    const float* row = Hmat + (size_t)r * 4 * D + h * D;
    float ss = 0.f, sd = 0.f;
    for (int d = lane; d < D; d += 64) {
        float v = row[d];
        ss += v * a_s[h * D + d];
        sd += v * a_d[h * D + d];
    }
#pragma unroll
    for (int o = 32; o > 0; o >>= 1) {
        ss += __shfl_down(ss, o);
        sd += __shfl_down(sd, o);
    }
    if (lane == 0) { es[r * 4 + h] = ss; ed[r * 4 + h] = sd; }
}

// ---------------- edge softmax + aggregate (one block per (node, graph)) ----------------
__global__ __launch_bounds__(256) void attn_kernel(const float* __restrict__ Hmat,
                                                   const float* __restrict__ es,
                                                   const float* __restrict__ ed,
                                                   const int* __restrict__ indptr,
                                                   const int* __restrict__ eidx,
                                                   const int* __restrict__ srcv,
                                                   const float* __restrict__ bias,
                                                   float* __restrict__ outf,
                                                   bf16_t* __restrict__ outb,
                                                   int D) {
    int d = blockIdx.x, b = blockIdx.y;
    int r = b * 257 + d;
    int t = threadIdx.x, wv = t >> 6, lane = t & 63;
    int e0 = indptr[d];
    int deg = indptr[d + 1] - e0;
    __shared__ float alpha[NNODE * 4];
    __shared__ int   ssh[NNODE];
    __shared__ float wred[4][8];
    __shared__ float mh[4], rh[4];
    float edh[4];
#pragma unroll
    for (int h = 0; h < 4; h++) edh[h] = ed[r * 4 + h];
    float lmax[4] = {-1e30f, -1e30f, -1e30f, -1e30f};
    for (int i = t; i < deg; i += 256) {
        int s = srcv[eidx[e0 + i]];
        ssh[i] = s;
        int rs = (b * 257 + s) * 4;
#pragma unroll
        for (int h = 0; h < 4; h++) {
            float v = es[rs + h] + edh[h];
            v = v > 0.f ? v : 0.2f * v;     // leaky_relu 0.2
            alpha[i * 4 + h] = v;
            lmax[h] = fmaxf(lmax[h], v);
        }
    }
#pragma unroll
    for (int h = 0; h < 4; h++) {
        float m = lmax[h];
#pragma unroll
        for (int o = 32; o > 0; o >>= 1) m = fmaxf(m, __shfl_down(m, o));
        if (lane == 0) wred[h][wv] = m;
    }
    __syncthreads();
    if (t < 4)
        mh[t] = fmaxf(fmaxf(wred[t][0], wred[t][1]), fmaxf(wred[t][2], wred[t][3]));
    __syncthreads();
    float lsum[4] = {0.f, 0.f, 0.f, 0.f};
    for (int i = t; i < deg; i += 256) {
#pragma unroll
        for (int h = 0; h < 4; h++) {
            float a = __expf(alpha[i * 4 + h] - mh[h]);
            alpha[i * 4 + h] = a;
            lsum[h] += a;
        }
    }
#pragma unroll
    for (int h = 0; h < 4; h++) {
        float s = lsum[h];
#pragma unroll
        for (int o = 32; o > 0; o >>= 1) s += __shfl_down(s, o);
        if (lane == 0) wred[h][wv] = s;
    }
    __syncthreads();
    if (t < 4)
        rh[t] = 1.f / (wred[t][0] + wred[t][1] + wred[t][2] + wred[t][3] + 1e-16f);
    __syncthreads();
    for (int i = t; i < deg; i += 256) {
#pragma unroll
        for (int h = 0; h < 4; h++) alpha[i * 4 + h] *= rh[h];
    }
    __syncthreads();
    if (t < D) {
        const float* base = Hmat + (size_t)(b * 257) * 4 * D + t;
        float a0 = 0.f, a1 = 0.f, a2 = 0.f, a3 = 0.f;
        for (int i = 0; i < deg; i++) {
            const float* hr = base + (size_t)ssh[i] * 4 * D;
            float l0 = alpha[i * 4 + 0], l1 = alpha[i * 4 + 1];
            float l2 = alpha[i * 4 + 2], l3 = alpha[i * 4 + 3];
            a0 += l0 * hr[0];
            a1 += l1 * hr[D];
            a2 += l2 * hr[2 * D];
            a3 += l3 * hr[3 * D];
        }
        float o = (a0 + a1 + a2 + a3) * 0.25f + bias[t];
        if (outb) outb[(size_t)r * D + t] = (bf16_t)o;
        else      outf[(size_t)r * D + t] = o;
    }
}

// ---------------- per-graph head: pool weights, weighted mean, MLP ----------------
__global__ __launch_bounds__(256) void head_kernel(const float* __restrict__ out2,
                                                   const float* __restrict__ Wp,
                                                   const float* __restrict__ bp,
                                                   const float* __restrict__ Wc1,
                                                   const float* __restrict__ bc1,
                                                   const float* __restrict__ Wc2,
                                                   const float* __restrict__ bc2,
                                                   float* __restrict__ outp) {
    int b = blockIdx.x, t = threadIdx.x, wv = t >> 6, lane = t & 63;
    __shared__ float wsh[NNODE];
    __shared__ float gsh[128];
    __shared__ float h1[64];
    const float* X = out2 + (size_t)b * 257 * 128;
    float wp0 = Wp[lane], wp1 = Wp[64 + lane], bp0 = bp[0];
    for (int n = wv; n < 257; n += 4) {
        const float* xr = X + n * 128;
        float s = xr[lane] * wp0 + xr[64 + lane] * wp1;
#pragma unroll
        for (int o = 32; o > 0; o >>= 1) s += __shfl_down(s, o);
        if (lane == 0) {
            float wvv = 1.f / (1.f + __expf(-(s + bp0)));
            wsh[n] = wvv;
            outp[32 + b * 257 + n] = wvv;   // atts output
        }
    }
    __syncthreads();
    if (t < 128) {
        float s = 0.f;
        for (int n = 0; n < 257; n++) s += X[n * 128 + t] * wsh[n];
        gsh[t] = s * (1.f / 257.f);
    }
    __syncthreads();
    if (t < 64) {
        float s = bc1[t];
        for (int k = 0; k < 128; k++) s += gsh[k] * Wc1[k * 64 + t];
        h1[t] = fmaxf(s, 0.f);
    }
    __syncthreads();
    if (t == 0) {
        float s = bc2[0];
        for (int j = 0; j < 64; j++) s += h1[j] * Wc2[j];
        outp[b] = 1.f / (1.f + expf(-s));   // preds output
    }
}

// ---------------- launch ----------------
extern "C" void kernel_launch(void* const* d_in, const int* in_sizes, int n_in,
                              void* d_out, int out_size, void* d_ws, size_t ws_size,
                              hipStream_t stream) {
    const float* fmap   = (const float*)d_in[0];
    const float* W1     = (const float*)d_in[1];
    const float* a_src1 = (const float*)d_in[2];
    const float* a_dst1 = (const float*)d_in[3];
    const float* b1     = (const float*)d_in[4];
    const float* W2     = (const float*)d_in[5];
    const float* a_src2 = (const float*)d_in[6];
    const float* a_dst2 = (const float*)d_in[7];
    const float* b2     = (const float*)d_in[8];
    const float* Wp     = (const float*)d_in[9];
    const float* bp     = (const float*)d_in[10];
    const float* Wc1    = (const float*)d_in[11];
    const float* bc1    = (const float*)d_in[12];
    const float* Wc2    = (const float*)d_in[13];
    const float* bc2    = (const float*)d_in[14];
    const int*   srcv   = (const int*)d_in[15];
    const int*   dstv   = (const int*)d_in[16];
    int E = in_sizes[15];
    float* outp = (float*)d_out;

    char* w = (char*)d_ws;
    size_t off = 0;
    auto alloc = [&](size_t bytes) -> void* {
        void* p = w + off;
        off += (bytes + 255) & ~(size_t)255;
        return p;
    };
    bf16_t* X    = (bf16_t*)alloc((size_t)MPAD * 2048 * sizeof(bf16_t));
    bf16_t* W1t  = (bf16_t*)alloc((size_t)1024 * 2048 * sizeof(bf16_t));
    bf16_t* W2t  = (bf16_t*)alloc((size_t)512 * 256 * sizeof(bf16_t));
    float*  H1   = (float*)alloc((size_t)MPAD * 1024 * sizeof(float));
    float*  es1  = (float*)alloc((size_t)MPAD * 4 * sizeof(float));
    float*  ed1  = (float*)alloc((size_t)MPAD * 4 * sizeof(float));
    bf16_t* out1 = (bf16_t*)alloc((size_t)MPAD * 256 * sizeof(bf16_t));
    float*  H2   = (float*)alloc((size_t)MPAD * 512 * sizeof(float));
    float*  es2  = (float*)alloc((size_t)MPAD * 4 * sizeof(float));
    float*  ed2  = (float*)alloc((size_t)MPAD * 4 * sizeof(float));
    float*  out2 = (float*)alloc((size_t)MPAD * 128 * sizeof(float));
    int*  indptr = (int*)alloc(258 * sizeof(int));
    int*  eidx   = (int*)alloc((size_t)E * sizeof(int));

    // zero X (disease rows + pad tail); zero out1 pad tail (read by GEMM2)
    hipMemsetAsync(X, 0, (size_t)MPAD * 2048 * sizeof(bf16_t), stream);
    hipMemsetAsync(out1 + (size_t)8224 * 256, 0,
                   (size_t)(MPAD - 8224) * 256 * sizeof(bf16_t), stream);

    prep_w_kernel<<<dim3(64, 32), dim3(32, 8), 0, stream>>>(W1, W1t, 2048, 1024);
    prep_w_kernel<<<dim3(8, 16), dim3(32, 8), 0, stream>>>(W2, W2t, 256, 512);
    prep_x_kernel<<<dim3(64, 8, NB), dim3(32, 8), 0, stream>>>(fmap, X);
    build_csr_kernel<<<1, 256, 0, stream>>>(dstv, E, indptr, eidx);

    // layer 1
    gemm_kernel<<<dim3(1024 / 128, MPAD / 128), 256, 0, stream>>>(X, W1t, H1, 2048, 1024);
    esed_kernel<<<NB * NNODE, 256, 0, stream>>>(H1, a_src1, a_dst1, es1, ed1, 256);
    attn_kernel<<<dim3(NNODE, NB), 256, 0, stream>>>(H1, es1, ed1, indptr, eidx, srcv,
                                                     b1, nullptr, out1, 256);
    // layer 2
    gemm_kernel<<<dim3(512 / 128, MPAD / 128), 256, 0, stream>>>(out1, W2t, H2, 256, 512);
    esed_kernel<<<NB * NNODE, 256, 0, stream>>>(H2, a_src2, a_dst2, es2, ed2, 128);
    attn_kernel<<<dim3(NNODE, NB), 256, 0, stream>>>(H2, es2, ed2, indptr, eidx, srcv,
                                                     b2, out2, nullptr, 128);
    // head
    head_kernel<<<NB, 256, 0, stream>>>(out2, Wp, bp, Wc1, bc1, Wc2, bc2, outp);

    (void)n_in; (void)out_size; (void)ws_size;
}

// Round 3
// 374.768 us; speedup vs baseline: 1.2785x; 1.1189x over previous
//
#include <hip/hip_runtime.h>

typedef __bf16 bf16_t;
typedef __bf16 bf16x8 __attribute__((ext_vector_type(8)));
typedef float f32x4 __attribute__((ext_vector_type(4)));

#define MPAD  8320   // 32*257 = 8224 padded to 65*128
#define NNODE 257
#define NB    32

__device__ __forceinline__ void gld_lds16(const bf16_t* g, bf16_t* l) {
    __builtin_amdgcn_global_load_lds(
        (const __attribute__((address_space(1))) void*)g,
        (__attribute__((address_space(3))) void*)l, 16, 0, 0);
}

// ---------------- prep: transpose + f32->bf16, 16B stores ----------------
// fmap [B, 2048, 256] f32 -> X [MPAD, 2048] bf16; 64c x 64n tile per block
__global__ __launch_bounds__(256) void prep_x_kernel(const float* __restrict__ fmap,
                                                     bf16_t* __restrict__ X) {
    __shared__ float tile[64][65];
    int c0 = blockIdx.x * 64, n0 = blockIdx.y * 64, b = blockIdx.z;
    int t = threadIdx.x;
    const float* f = fmap + (size_t)b * 2048 * 256;
    int ln = t & 63, lc = t >> 6;
#pragma unroll
    for (int i = 0; i < 16; i++) {
        int c = lc + i * 4;
        tile[c][ln] = f[(size_t)(c0 + c) * 256 + n0 + ln];
    }
    __syncthreads();
    int sn = t >> 3, sc = (t & 7) * 8;
#pragma unroll
    for (int half = 0; half < 2; half++) {
        int n = sn + half * 32;
        bf16_t tmp[8];
#pragma unroll
        for (int j = 0; j < 8; j++) tmp[j] = (bf16_t)tile[sc + j][n];
        *(bf16x8*)&X[(size_t)(b * 257 + n0 + n) * 2048 + c0 + sc] = *(bf16x8*)tmp;
    }
}

// W [K, N] f32 -> Wt [N, K] bf16
__global__ __launch_bounds__(256) void prep_w_kernel(const float* __restrict__ W,
                                                     bf16_t* __restrict__ Wt,
                                                     int K, int N) {
    __shared__ float tile[32][33];
    int k0 = blockIdx.x * 32, n0 = blockIdx.y * 32;
    int tx = threadIdx.x, ty = threadIdx.y;
#pragma unroll
    for (int i = 0; i < 4; i++)
        tile[ty + i * 8][tx] = W[(size_t)(k0 + ty + i * 8) * N + n0 + tx];
    __syncthreads();
#pragma unroll
    for (int i = 0; i < 4; i++)
        Wt[(size_t)(n0 + ty + i * 8) * K + k0 + tx] = (bf16_t)tile[tx][ty + i * 8];
}

// ---------------- CSR by dst (single block) ----------------
__global__ void build_csr_kernel(const int* __restrict__ dstv, int E,
                                 int* __restrict__ indptr, int* __restrict__ eidx) {
    __shared__ int cnt[258];
    __shared__ int off[258];
    int t = threadIdx.x;
    for (int i = t; i < 258; i += 256) cnt[i] = 0;
    __syncthreads();
    for (int e = t; e < E; e += 256) atomicAdd(&cnt[dstv[e] + 1], 1);
    __syncthreads();
    if (t == 0) {
        int s = 0;
        for (int i = 0; i < 258; i++) { s += cnt[i]; off[i] = s; }
    }
    __syncthreads();
    for (int i = t; i < 258; i += 256) indptr[i] = off[i];
    __syncthreads();
    for (int e = t; e < E; e += 256) {
        int p = atomicAdd(&off[dstv[e]], 1);
        eidx[p] = e;
    }
}

// ---------------- pipelined bf16 MFMA GEMM: C[M,N] = A[M,K] * Bt[N,K]^T, C bf16 ----------------
// 128x128 tile, BK=32, 3-stage LDS pipeline, raw s_barrier + fine vmcnt (no vmcnt(0) drain).
__global__ __launch_bounds__(256) void gemm_kernel(const bf16_t* __restrict__ A,
                                                   const bf16_t* __restrict__ Bt,
                                                   bf16_t* __restrict__ C,
                                                   int K, int N) {
    __shared__ __align__(16) bf16_t sm[3 * 8192];   // 3 stages x (As 4096 + Bs 4096)
    int row0 = blockIdx.y * 128, col0 = blockIdx.x * 128;
    int t = threadIdx.x;
    int wave = t >> 6, lane = t & 63;
    int wr = wave >> 1, wc = wave & 1;
    int ch0 = wave * 2;
    int srow = lane >> 2;
    int scol = (lane & 3) * 8;
    const bf16_t* Abase = A + (size_t)row0 * K;
    const bf16_t* Bbase = Bt + (size_t)col0 * K;
    f32x4 acc[4][4] = {};
    int fr = lane & 15;
    int kq = (lane >> 4) * 8;
    int nk = K >> 5;
    auto issue = [&](int kt, int stage) {
        bf16_t* As = sm + stage * 8192;
        bf16_t* Bs = As + 4096;
        int k0 = kt << 5;
#pragma unroll
        for (int c = 0; c < 2; c++) {
            int chunk = ch0 + c;
            int row = chunk * 16 + srow;
            gld_lds16(Abase + (size_t)row * K + k0 + scol, &As[chunk * 512]);
            gld_lds16(Bbase + (size_t)row * K + k0 + scol, &Bs[chunk * 512]);
        }
    };
    issue(0, 0);
    if (nk > 1) issue(1, 1);
    for (int k = 0; k < nk; k++) {
        int cur = k % 3;
        if (k + 2 < nk) {
            issue(k + 2, (k + 2) % 3);
            asm volatile("s_waitcnt vmcnt(8)" ::: "memory");   // tile k's 4 loads done
        } else if (k + 1 < nk) {
            asm volatile("s_waitcnt vmcnt(4)" ::: "memory");
        } else {
            asm volatile("s_waitcnt vmcnt(0)" ::: "memory");
        }
        __builtin_amdgcn_s_barrier();
        const bf16_t* As = sm + cur * 8192;
        const bf16_t* Bs = As + 4096;
        bf16x8 af[4], bfv[4];
#pragma unroll
        for (int mr = 0; mr < 4; mr++)
            af[mr] = *(const bf16x8*)&As[(wr * 64 + mr * 16 + fr) * 32 + kq];
#pragma unroll
        for (int nc = 0; nc < 4; nc++)
            bfv[nc] = *(const bf16x8*)&Bs[(wc * 64 + nc * 16 + fr) * 32 + kq];
#pragma unroll
        for (int mr = 0; mr < 4; mr++)
#pragma unroll
            for (int nc = 0; nc < 4; nc++)
                acc[mr][nc] = __builtin_amdgcn_mfma_f32_16x16x32_bf16(
                    af[mr], bfv[nc], acc[mr][nc], 0, 0, 0);
        asm volatile("s_waitcnt lgkmcnt(0)" ::: "memory");   // ds_reads of cur complete
        __builtin_amdgcn_s_barrier();                        // next iter may overwrite cur
    }
#pragma unroll
    for (int mr = 0; mr < 4; mr++) {
        int crow = row0 + wr * 64 + mr * 16 + (lane >> 4) * 4;
#pragma unroll
        for (int nc = 0; nc < 4; nc++) {
            int ccol = col0 + wc * 64 + nc * 16 + (lane & 15);
#pragma unroll
            for (int r = 0; r < 4; r++)
                C[(size_t)(crow + r) * N + ccol] = (bf16_t)acc[mr][nc][r];
        }
    }
}

// ---------------- es/ed per-row head dots (bf16 H, vectorized) ----------------
template<int D>
__global__ __launch_bounds__(256) void esed_kernel(const bf16_t* __restrict__ Hb,
                                                   const float* __restrict__ a_s,
                                                   const float* __restrict__ a_d,
                                                   float* __restrict__ es,
                                                   float* __restrict__ ed) {
    constexpr int VPL = D / 64;
    int r = blockIdx.x;
    int h = threadIdx.x >> 6, lane = threadIdx.x & 63;
    const bf16_t* row = Hb + (size_t)r * 4 * D + h * D + lane * VPL;
    const float* asp = a_s + h * D + lane * VPL;
    const float* adp = a_d + h * D + lane * VPL;
    bf16_t xv[VPL];
    __builtin_memcpy(xv, row, VPL * 2);
    float ss = 0.f, sd = 0.f;
#pragma unroll
    for (int v = 0; v < VPL; v++) {
        float x = (float)xv[v];
        ss += x * asp[v];
        sd += x * adp[v];
    }
#pragma unroll
    for (int o = 32; o > 0; o >>= 1) {
        ss += __shfl_down(ss, o);
        sd += __shfl_down(sd, o);
    }
    if (lane == 0) { es[r * 4 + h] = ss; ed[r * 4 + h] = sd; }
}

// ---------------- edge softmax + aggregate (block per (node, graph), bf16 H) ----------------
template<int D>
__global__ __launch_bounds__(256) void attn_kernel(const bf16_t* __restrict__ Hb,
                                                   const float* __restrict__ es,
                                                   const float* __restrict__ ed,
                                                   const int* __restrict__ indptr,
                                                   const int* __restrict__ eidx,
                                                   const int* __restrict__ srcv,
                                                   const float* __restrict__ bias,
                                                   float* __restrict__ outf,
                                                   bf16_t* __restrict__ outb) {
    constexpr int VPL = D / 64;
    int d = blockIdx.x, b = blockIdx.y;
    int r = b * 257 + d;
    int t = threadIdx.x, wv = t >> 6, lane = t & 63;
    int e0 = indptr[d];
    int deg = indptr[d + 1] - e0;
    __shared__ float alpha[NNODE * 4];
    __shared__ int   ssh[NNODE];
    __shared__ float wred[4][8];
    __shared__ float mh4[4], rh4[4];
    __shared__ float osh[4][D];
    const float4 edv = *(const float4*)&ed[r * 4];
    float edh[4] = {edv.x, edv.y, edv.z, edv.w};
    float lmax[4] = {-1e30f, -1e30f, -1e30f, -1e30f};
    for (int i = t; i < deg; i += 256) {
        int s = srcv[eidx[e0 + i]];
        ssh[i] = s;
        float4 e4 = *(const float4*)&es[(b * 257 + s) * 4];
        float ev[4] = {e4.x, e4.y, e4.z, e4.w};
#pragma unroll
        for (int h = 0; h < 4; h++) {
            float v = ev[h] + edh[h];
            v = v > 0.f ? v : 0.2f * v;     // leaky_relu 0.2
            alpha[i * 4 + h] = v;
            lmax[h] = fmaxf(lmax[h], v);
        }
    }
#pragma unroll
    for (int h = 0; h < 4; h++) {
        float m = lmax[h];
#pragma unroll
        for (int o = 32; o > 0; o >>= 1) m = fmaxf(m, __shfl_down(m, o));
        if (lane == 0) wred[h][wv] = m;
    }
    __syncthreads();
    if (t < 4)
        mh4[t] = fmaxf(fmaxf(wred[t][0], wred[t][1]), fmaxf(wred[t][2], wred[t][3]));
    __syncthreads();
    float lsum[4] = {0.f, 0.f, 0.f, 0.f};
    for (int i = t; i < deg; i += 256) {
#pragma unroll
        for (int h = 0; h < 4; h++) {
            float a = __expf(alpha[i * 4 + h] - mh4[h]);
            alpha[i * 4 + h] = a;
            lsum[h] += a;
        }
    }
#pragma unroll
    for (int h = 0; h < 4; h++) {
        float s = lsum[h];
#pragma unroll
        for (int o = 32; o > 0; o >>= 1) s += __shfl_down(s, o);
        if (lane == 0) wred[h][wv] = s;
    }
    __syncthreads();
    if (t < 4)
        rh4[t] = 1.f / (wred[t][0] + wred[t][1] + wred[t][2] + wred[t][3] + 1e-16f);
    __syncthreads();
    for (int i = t; i < deg; i += 256) {
#pragma unroll
        for (int h = 0; h < 4; h++) alpha[i * 4 + h] *= rh4[h];
    }
    __syncthreads();
    // aggregate: wave wv owns head wv; lane owns VPL consecutive dims (8B/4B loads)
    float acc[VPL] = {};
    const bf16_t* hb = Hb + (size_t)(b * 257) * 4 * D + wv * D + lane * VPL;
    for (int i = 0; i < deg; i++) {
        float a = alpha[i * 4 + wv];
        const bf16_t* hr = hb + (size_t)ssh[i] * 4 * D;
        bf16_t xv[VPL];
        __builtin_memcpy(xv, hr, VPL * 2);
#pragma unroll
        for (int v = 0; v < VPL; v++) acc[v] += a * (float)xv[v];
    }
#pragma unroll
    for (int v = 0; v < VPL; v++) osh[wv][lane * VPL + v] = acc[v];
    __syncthreads();
    if (t < D) {
        float o = (osh[0][t] + osh[1][t] + osh[2][t] + osh[3][t]) * 0.25f + bias[t];
        if (outb) outb[(size_t)r * D + t] = (bf16_t)o;
        else      outf[(size_t)r * D + t] = o;
    }
}

// ---------------- per-graph head: pool weights, weighted mean, MLP ----------------
__global__ __launch_bounds__(256) void head_kernel(const float* __restrict__ out2,
                                                   const float* __restrict__ Wp,
                                                   const float* __restrict__ bp,
                                                   const float* __restrict__ Wc1,
                                                   const float* __restrict__ bc1,
                                                   const float* __restrict__ Wc2,
                                                   const float* __restrict__ bc2,
                                                   float* __restrict__ outp) {
    int b = blockIdx.x, t = threadIdx.x, wv = t >> 6, lane = t & 63;
    __shared__ float wsh[NNODE];
    __shared__ float gpart[2][128];
    __shared__ float gsh[128];
    __shared__ float h1[64];
    const float* X = out2 + (size_t)b * 257 * 128;
    float wp0 = Wp[lane], wp1 = Wp[64 + lane], bp0 = bp[0];
    for (int n = wv; n < 257; n += 4) {
        const float* xr = X + n * 128;
        float s = xr[lane] * wp0 + xr[64 + lane] * wp1;
#pragma unroll
        for (int o = 32; o > 0; o >>= 1) s += __shfl_down(s, o);
        if (lane == 0) {
            float wvv = 1.f / (1.f + __expf(-(s + bp0)));
            wsh[n] = wvv;
            outp[32 + b * 257 + n] = wvv;   // atts output
        }
    }
    __syncthreads();
    {
        int dim = t & 127, half = t >> 7;
        float s = 0.f;
        for (int n = half; n < 257; n += 2) s += X[n * 128 + dim] * wsh[n];
        gpart[half][dim] = s;
    }
    __syncthreads();
    if (t < 128) gsh[t] = (gpart[0][t] + gpart[1][t]) * (1.f / 257.f);
    __syncthreads();
    if (t < 64) {
        float s = bc1[t];
        for (int k = 0; k < 128; k++) s += gsh[k] * Wc1[k * 64 + t];
        h1[t] = fmaxf(s, 0.f);
    }
    __syncthreads();
    if (t == 0) {
        float s = bc2[0];
        for (int j = 0; j < 64; j++) s += h1[j] * Wc2[j];
        outp[b] = 1.f / (1.f + expf(-s));   // preds output
    }
}

// ---------------- launch ----------------
extern "C" void kernel_launch(void* const* d_in, const int* in_sizes, int n_in,
                              void* d_out, int out_size, void* d_ws, size_t ws_size,
                              hipStream_t stream) {
    const float* fmap   = (const float*)d_in[0];
    const float* W1     = (const float*)d_in[1];
    const float* a_src1 = (const float*)d_in[2];
    const float* a_dst1 = (const float*)d_in[3];
    const float* b1     = (const float*)d_in[4];
    const float* W2     = (const float*)d_in[5];
    const float* a_src2 = (const float*)d_in[6];
    const float* a_dst2 = (const float*)d_in[7];
    const float* b2     = (const float*)d_in[8];
    const float* Wp     = (const float*)d_in[9];
    const float* bp     = (const float*)d_in[10];
    const float* Wc1    = (const float*)d_in[11];
    const float* bc1    = (const float*)d_in[12];
    const float* Wc2    = (const float*)d_in[13];
    const float* bc2    = (const float*)d_in[14];
    const int*   srcv   = (const int*)d_in[15];
    const int*   dstv   = (const int*)d_in[16];
    int E = in_sizes[15];
    float* outp = (float*)d_out;

    char* w = (char*)d_ws;
    size_t off = 0;
    auto alloc = [&](size_t bytes) -> void* {
        void* p = w + off;
        off += (bytes + 255) & ~(size_t)255;
        return p;
    };
    bf16_t* X    = (bf16_t*)alloc((size_t)MPAD * 2048 * sizeof(bf16_t));
    bf16_t* W1t  = (bf16_t*)alloc((size_t)1024 * 2048 * sizeof(bf16_t));
    bf16_t* W2t  = (bf16_t*)alloc((size_t)512 * 256 * sizeof(bf16_t));
    bf16_t* H1   = (bf16_t*)alloc((size_t)MPAD * 1024 * sizeof(bf16_t));
    float*  es1  = (float*)alloc((size_t)MPAD * 4 * sizeof(float));
    float*  ed1  = (float*)alloc((size_t)MPAD * 4 * sizeof(float));
    bf16_t* out1 = (bf16_t*)alloc((size_t)MPAD * 256 * sizeof(bf16_t));
    bf16_t* H2   = (bf16_t*)alloc((size_t)MPAD * 512 * sizeof(bf16_t));
    float*  es2  = (float*)alloc((size_t)MPAD * 4 * sizeof(float));
    float*  ed2  = (float*)alloc((size_t)MPAD * 4 * sizeof(float));
    float*  out2 = (float*)alloc((size_t)MPAD * 128 * sizeof(float));
    int*  indptr = (int*)alloc(258 * sizeof(int));
    int*  eidx   = (int*)alloc((size_t)E * sizeof(int));

    // zero X (disease rows + pad tail); zero out1 pad tail (read by GEMM2)
    hipMemsetAsync(X, 0, (size_t)MPAD * 2048 * sizeof(bf16_t), stream);
    hipMemsetAsync(out1 + (size_t)8224 * 256, 0,
                   (size_t)(MPAD - 8224) * 256 * sizeof(bf16_t), stream);

    prep_w_kernel<<<dim3(64, 32), dim3(32, 8), 0, stream>>>(W1, W1t, 2048, 1024);
    prep_w_kernel<<<dim3(8, 16), dim3(32, 8), 0, stream>>>(W2, W2t, 256, 512);
    prep_x_kernel<<<dim3(32, 4, NB), 256, 0, stream>>>(fmap, X);
    build_csr_kernel<<<1, 256, 0, stream>>>(dstv, E, indptr, eidx);

    // layer 1
    gemm_kernel<<<dim3(1024 / 128, MPAD / 128), 256, 0, stream>>>(X, W1t, H1, 2048, 1024);
    esed_kernel<256><<<NB * NNODE, 256, 0, stream>>>(H1, a_src1, a_dst1, es1, ed1);
    attn_kernel<256><<<dim3(NNODE, NB), 256, 0, stream>>>(H1, es1, ed1, indptr, eidx,
                                                          srcv, b1, nullptr, out1);
    // layer 2
    gemm_kernel<<<dim3(512 / 128, MPAD / 128), 256, 0, stream>>>(out1, W2t, H2, 256, 512);
    esed_kernel<128><<<NB * NNODE, 256, 0, stream>>>(H2, a_src2, a_dst2, es2, ed2);
    attn_kernel<128><<<dim3(NNODE, NB), 256, 0, stream>>>(H2, es2, ed2, indptr, eidx,
                                                          srcv, b2, out2, nullptr);
    // head
    head_kernel<<<NB, 256, 0, stream>>>(out2, Wp, bp, Wc1, bc1, Wc2, bc2, outp);

    (void)n_in; (void)out_size; (void)ws_size;
}

// Round 4
// 354.975 us; speedup vs baseline: 1.3498x; 1.0558x over previous
//
#include <hip/hip_runtime.h>

typedef __bf16 bf16_t;
typedef __bf16 bf16x8 __attribute__((ext_vector_type(8)));
typedef float f32x4 __attribute__((ext_vector_type(4)));

#define MPAD  8320   // 32*257 = 8224 padded to 65*128
#define NNODE 257
#define NB    32

__device__ __forceinline__ void gld_lds16(const bf16_t* g, bf16_t* l) {
    __builtin_amdgcn_global_load_lds(
        (const __attribute__((address_space(1))) void*)g,
        (__attribute__((address_space(3))) void*)l, 16, 0, 0);
}

// ================= setup: prep_w1 + prep_w2 + prep_x + zeroing + CSR, one dispatch =================
// block ranges: [0,2048) W1t | [2048,2176) W2t | [2176,6272) X transpose |
// [6272,6402) zero es/ed (130*4KB) | [6402,6530) zero X disease/pad rows | [6530,6542) zero out1 tail | 6542 CSR
__global__ __launch_bounds__(256) void setup_kernel(const float* __restrict__ W1, bf16_t* __restrict__ W1t,
                                                    const float* __restrict__ W2, bf16_t* __restrict__ W2t,
                                                    const float* __restrict__ fmap, bf16_t* __restrict__ X,
                                                    const int* __restrict__ dstv, int E,
                                                    int* __restrict__ indptr, int* __restrict__ eidx,
                                                    float* __restrict__ zbase, bf16_t* __restrict__ out1) {
    __shared__ float smem[64 * 65];
    int idx = blockIdx.x, t = threadIdx.x;
    if (idx < 2176) {
        // ---- weight transpose: W [K,N] f32 -> Wt [N,K] bf16, 32x32 tiles ----
        const float* W; bf16_t* Wt; int K, N, kt, nt;
        if (idx < 2048) { W = W1; Wt = W1t; K = 2048; N = 1024; kt = idx >> 5; nt = idx & 31; }
        else { int l = idx - 2048; W = W2; Wt = W2t; K = 256; N = 512; kt = l >> 4; nt = l & 15; }
        int k0 = kt * 32, n0 = nt * 32;
        int tx = t & 31, ty = t >> 5;
#pragma unroll
        for (int i = 0; i < 4; i++)
            smem[(ty + i * 8) * 33 + tx] = W[(size_t)(k0 + ty + i * 8) * N + n0 + tx];
        __syncthreads();
#pragma unroll
        for (int i = 0; i < 4; i++)
            Wt[(size_t)(n0 + ty + i * 8) * K + k0 + tx] = (bf16_t)smem[tx * 33 + ty + i * 8];
    } else if (idx < 6272) {
        // ---- fmap [B,2048,256] f32 -> X [MPAD,2048] bf16 (64c x 64n tile) ----
        int local = idx - 2176;
        int ct = local & 31, rem = local >> 5;
        int nt = rem & 3, b = rem >> 2;
        int c0 = ct * 64, n0 = nt * 64;
        const float* f = fmap + (size_t)b * 2048 * 256;
        int ln = t & 63, lc = t >> 6;
#pragma unroll
        for (int i = 0; i < 16; i++) {
            int c = lc + i * 4;
            smem[c * 65 + ln] = f[(size_t)(c0 + c) * 256 + n0 + ln];
        }
        __syncthreads();
        int sn = t >> 3, sc = (t & 7) * 8;
#pragma unroll
        for (int half = 0; half < 2; half++) {
            int n = sn + half * 32;
            bf16_t tmp[8];
#pragma unroll
            for (int j = 0; j < 8; j++) tmp[j] = (bf16_t)smem[(sc + j) * 65 + n];
            *(bf16x8*)&X[(size_t)(b * 257 + n0 + n) * 2048 + c0 + sc] = *(bf16x8*)tmp;
        }
    } else if (idx < 6402) {
        // ---- zero es1/ed1/es2/ed2 (contiguous 130*4096 B) ----
        int local = idx - 6272;
        uint4* p = (uint4*)zbase + (size_t)local * 256;
        p[t] = uint4{0, 0, 0, 0};
    } else if (idx < 6530) {
        // ---- zero X disease rows + pad rows (4096 B each) ----
        int i = idx - 6402;
        int row = (i < 32) ? (i * 257 + 256) : (8224 + (i - 32));
        uint4* p = (uint4*)(X + (size_t)row * 2048);
        p[t] = uint4{0, 0, 0, 0};
    } else if (idx < 6542) {
        // ---- zero out1 pad tail (12*4096 B) ----
        int local = idx - 6530;
        uint4* p = (uint4*)((char*)(out1 + (size_t)8224 * 256) + (size_t)local * 4096);
        p[t] = uint4{0, 0, 0, 0};
    } else {
        // ---- CSR by dst ----
        __shared__ int cnt[258];
        __shared__ int off[258];
        for (int i = t; i < 258; i += 256) cnt[i] = 0;
        __syncthreads();
        for (int e = t; e < E; e += 256) atomicAdd(&cnt[dstv[e] + 1], 1);
        __syncthreads();
        if (t == 0) {
            int s = 0;
            for (int i = 0; i < 258; i++) { s += cnt[i]; off[i] = s; }
        }
        __syncthreads();
        for (int i = t; i < 258; i += 256) indptr[i] = off[i];
        __syncthreads();
        for (int e = t; e < E; e += 256) {
            int p = atomicAdd(&off[dstv[e]], 1);
            eidx[p] = e;
        }
    }
}

// ================= GEMM: C[M,N] = A[M,K]*Bt[N,K]^T, bf16 out, fused es/ed epilogue =================
// 128x128 block tile, 2 waves (wave w: rows w*64..+63, all 128 cols), 4x8 acc of 16x16x32 MFMA,
// 3-stage LDS pipeline with fine vmcnt; per-wave stages its own A rows + half of B.
__global__ __launch_bounds__(128, 2) void gemm_kernel(const bf16_t* __restrict__ A,
                                                      const bf16_t* __restrict__ Bt,
                                                      bf16_t* __restrict__ C,
                                                      const float* __restrict__ asrc,
                                                      const float* __restrict__ adst,
                                                      float* __restrict__ es,
                                                      float* __restrict__ ed,
                                                      int K, int N, int headD) {
    __shared__ __align__(16) bf16_t sm[3 * 8192];   // stage: As 128x32 (4096) + Bs 128x32 (4096)
    int row0 = blockIdx.y * 128, col0 = blockIdx.x * 128;
    int t = threadIdx.x;
    int wave = t >> 6, lane = t & 63;
    int srow = lane >> 2, scol = (lane & 3) * 8;
    const bf16_t* Abase = A + (size_t)row0 * K;
    const bf16_t* Bbase = Bt + (size_t)col0 * K;
    f32x4 acc[4][8] = {};
    int fr = lane & 15;
    int kq = (lane >> 4) * 8;
    int nk = K >> 5;
    auto issue = [&](int kt, int stage) {
        bf16_t* As = sm + stage * 8192;
        bf16_t* Bs = As + 4096;
        int k0 = kt << 5;
#pragma unroll
        for (int c = 0; c < 4; c++) {
            int chunk = wave * 4 + c;
            int row = chunk * 16 + srow;
            gld_lds16(Abase + (size_t)row * K + k0 + scol, &As[chunk * 512]);
            gld_lds16(Bbase + (size_t)row * K + k0 + scol, &Bs[chunk * 512]);
        }
    };
    issue(0, 0);
    if (nk > 1) issue(1, 1);
    for (int k = 0; k < nk; k++) {
        int cur = k % 3;
        if (k + 2 < nk) {
            issue(k + 2, (k + 2) % 3);
            asm volatile("s_waitcnt vmcnt(16)" ::: "memory");   // this wave's tile-k 8 loads done
        } else if (k + 1 < nk) {
            asm volatile("s_waitcnt vmcnt(8)" ::: "memory");
        } else {
            asm volatile("s_waitcnt vmcnt(0)" ::: "memory");
        }
        __builtin_amdgcn_s_barrier();                           // all waves' tile-k DMAs landed
        const bf16_t* As = sm + cur * 8192;
        const bf16_t* Bs = As + 4096;
        bf16x8 af[4], bfv[8];
#pragma unroll
        for (int mr = 0; mr < 4; mr++)
            af[mr] = *(const bf16x8*)&As[(wave * 64 + mr * 16 + fr) * 32 + kq];
#pragma unroll
        for (int nc = 0; nc < 8; nc++)
            bfv[nc] = *(const bf16x8*)&Bs[(nc * 16 + fr) * 32 + kq];
#pragma unroll
        for (int mr = 0; mr < 4; mr++)
#pragma unroll
            for (int nc = 0; nc < 8; nc++)
                acc[mr][nc] = __builtin_amdgcn_mfma_f32_16x16x32_bf16(
                    af[mr], bfv[nc], acc[mr][nc], 0, 0, 0);
        asm volatile("s_waitcnt lgkmcnt(0)" ::: "memory");      // stage cur fully consumed
        __builtin_amdgcn_s_barrier();
    }
    // ---- C store (C/D layout: col=lane&15, row=(lane>>4)*4+reg) ----
#pragma unroll
    for (int mr = 0; mr < 4; mr++) {
        int crow = row0 + wave * 64 + mr * 16 + (lane >> 4) * 4;
#pragma unroll
        for (int nc = 0; nc < 8; nc++) {
            int ccol = col0 + nc * 16 + (lane & 15);
#pragma unroll
            for (int r = 0; r < 4; r++)
                C[(size_t)(crow + r) * N + ccol] = (bf16_t)acc[mr][nc][r];
        }
    }
    // ---- fused es/ed: per-row partial dot over this block's 128 cols (one head) ----
    int h = col0 / headD;
    float as_v[8], ad_v[8];
#pragma unroll
    for (int nc = 0; nc < 8; nc++) {
        int ccol = col0 + nc * 16 + (lane & 15);
        as_v[nc] = asrc[ccol];
        ad_v[nc] = adst[ccol];
    }
#pragma unroll
    for (int mr = 0; mr < 4; mr++)
#pragma unroll
        for (int r = 0; r < 4; r++) {
            float ps = 0.f, pd = 0.f;
#pragma unroll
            for (int nc = 0; nc < 8; nc++) {
                float v = acc[mr][nc][r];
                ps += v * as_v[nc];
                pd += v * ad_v[nc];
            }
#pragma unroll
            for (int m = 1; m < 16; m <<= 1) {
                ps += __shfl_xor(ps, m);
                pd += __shfl_xor(pd, m);
            }
            if ((lane & 15) == 0) {
                int row = row0 + wave * 64 + mr * 16 + (lane >> 4) * 4 + r;
                atomicAdd(&es[row * 4 + h], ps);
                atomicAdd(&ed[row * 4 + h], pd);
            }
        }
}

// ================= edge softmax + aggregate (block per (node, graph), bf16 H) =================
template<int D>
__global__ __launch_bounds__(256) void attn_kernel(const bf16_t* __restrict__ Hb,
                                                   const float* __restrict__ es,
                                                   const float* __restrict__ ed,
                                                   const int* __restrict__ indptr,
                                                   const int* __restrict__ eidx,
                                                   const int* __restrict__ srcv,
                                                   const float* __restrict__ bias,
                                                   float* __restrict__ outf,
                                                   bf16_t* __restrict__ outb) {
    constexpr int VPL = D / 64;
    int d = blockIdx.x, b = blockIdx.y;
    int r = b * 257 + d;
    int t = threadIdx.x, wv = t >> 6, lane = t & 63;
    int e0 = indptr[d];
    int deg = indptr[d + 1] - e0;
    __shared__ float alpha[NNODE * 4];
    __shared__ int   ssh[NNODE];
    __shared__ float wred[4][8];
    __shared__ float mh4[4], rh4[4];
    __shared__ float osh[4][D];
    const float4 edv = *(const float4*)&ed[r * 4];
    float edh[4] = {edv.x, edv.y, edv.z, edv.w};
    float lmax[4] = {-1e30f, -1e30f, -1e30f, -1e30f};
    for (int i = t; i < deg; i += 256) {
        int s = srcv[eidx[e0 + i]];
        ssh[i] = s;
        float4 e4 = *(const float4*)&es[(b * 257 + s) * 4];
        float ev[4] = {e4.x, e4.y, e4.z, e4.w};
#pragma unroll
        for (int h = 0; h < 4; h++) {
            float v = ev[h] + edh[h];
            v = v > 0.f ? v : 0.2f * v;     // leaky_relu 0.2
            alpha[i * 4 + h] = v;
            lmax[h] = fmaxf(lmax[h], v);
        }
    }
#pragma unroll
    for (int h = 0; h < 4; h++) {
        float m = lmax[h];
#pragma unroll
        for (int o = 32; o > 0; o >>= 1) m = fmaxf(m, __shfl_down(m, o));
        if (lane == 0) wred[h][wv] = m;
    }
    __syncthreads();
    if (t < 4)
        mh4[t] = fmaxf(fmaxf(wred[t][0], wred[t][1]), fmaxf(wred[t][2], wred[t][3]));
    __syncthreads();
    float lsum[4] = {0.f, 0.f, 0.f, 0.f};
    for (int i = t; i < deg; i += 256) {
#pragma unroll
        for (int h = 0; h < 4; h++) {
            float a = __expf(alpha[i * 4 + h] - mh4[h]);
            alpha[i * 4 + h] = a;
            lsum[h] += a;
        }
    }
#pragma unroll
    for (int h = 0; h < 4; h++) {
        float s = lsum[h];
#pragma unroll
        for (int o = 32; o > 0; o >>= 1) s += __shfl_down(s, o);
        if (lane == 0) wred[h][wv] = s;
    }
    __syncthreads();
    if (t < 4)
        rh4[t] = 1.f / (wred[t][0] + wred[t][1] + wred[t][2] + wred[t][3] + 1e-16f);
    __syncthreads();
    // aggregate (1/denom folded): wave wv = head wv; lane covers VPL consecutive dims
    float rh = rh4[wv];
    float acc[VPL] = {};
    const bf16_t* hb = Hb + (size_t)(b * 257) * 4 * D + wv * D + lane * VPL;
    for (int i = 0; i < deg; i++) {
        float a = alpha[i * 4 + wv] * rh;
        const bf16_t* hr = hb + (size_t)ssh[i] * 4 * D;
        bf16_t xv[VPL];
        __builtin_memcpy(xv, hr, VPL * 2);
#pragma unroll
        for (int v = 0; v < VPL; v++) acc[v] += a * (float)xv[v];
    }
#pragma unroll
    for (int v = 0; v < VPL; v++) osh[wv][lane * VPL + v] = acc[v];
    __syncthreads();
    if (t < D) {
        float o = (osh[0][t] + osh[1][t] + osh[2][t] + osh[3][t]) * 0.25f + bias[t];
        if (outb) outb[(size_t)r * D + t] = (bf16_t)o;
        else      outf[(size_t)r * D + t] = o;
    }
}

// ================= per-graph head: pool weights, weighted mean, MLP =================
__global__ __launch_bounds__(256) void head_kernel(const float* __restrict__ out2,
                                                   const float* __restrict__ Wp,
                                                   const float* __restrict__ bp,
                                                   const float* __restrict__ Wc1,
                                                   const float* __restrict__ bc1,
                                                   const float* __restrict__ Wc2,
                                                   const float* __restrict__ bc2,
                                                   float* __restrict__ outp) {
    int b = blockIdx.x, t = threadIdx.x, wv = t >> 6, lane = t & 63;
    __shared__ float wsh[NNODE];
    __shared__ float gpart[2][128];
    __shared__ float gsh[128];
    __shared__ float h1[64];
    const float* X = out2 + (size_t)b * 257 * 128;
    float wp0 = Wp[lane], wp1 = Wp[64 + lane], bp0 = bp[0];
    for (int n = wv; n < 257; n += 4) {
        const float* xr = X + n * 128;
        float s = xr[lane] * wp0 + xr[64 + lane] * wp1;
#pragma unroll
        for (int o = 32; o > 0; o >>= 1) s += __shfl_down(s, o);
        if (lane == 0) {
            float wvv = 1.f / (1.f + __expf(-(s + bp0)));
            wsh[n] = wvv;
            outp[32 + b * 257 + n] = wvv;   // atts output
        }
    }
    __syncthreads();
    {
        int dim = t & 127, half = t >> 7;
        float s = 0.f;
        for (int n = half; n < 257; n += 2) s += X[n * 128 + dim] * wsh[n];
        gpart[half][dim] = s;
    }
    __syncthreads();
    if (t < 128) gsh[t] = (gpart[0][t] + gpart[1][t]) * (1.f / 257.f);
    __syncthreads();
    if (t < 64) {
        float s = bc1[t];
        for (int k = 0; k < 128; k++) s += gsh[k] * Wc1[k * 64 + t];
        h1[t] = fmaxf(s, 0.f);
    }
    __syncthreads();
    if (t == 0) {
        float s = bc2[0];
        for (int j = 0; j < 64; j++) s += h1[j] * Wc2[j];
        outp[b] = 1.f / (1.f + expf(-s));   // preds output
    }
}

// ================= launch =================
extern "C" void kernel_launch(void* const* d_in, const int* in_sizes, int n_in,
                              void* d_out, int out_size, void* d_ws, size_t ws_size,
                              hipStream_t stream) {
    const float* fmap   = (const float*)d_in[0];
    const float* W1     = (const float*)d_in[1];
    const float* a_src1 = (const float*)d_in[2];
    const float* a_dst1 = (const float*)d_in[3];
    const float* b1     = (const float*)d_in[4];
    const float* W2     = (const float*)d_in[5];
    const float* a_src2 = (const float*)d_in[6];
    const float* a_dst2 = (const float*)d_in[7];
    const float* b2     = (const float*)d_in[8];
    const float* Wp     = (const float*)d_in[9];
    const float* bp     = (const float*)d_in[10];
    const float* Wc1    = (const float*)d_in[11];
    const float* bc1    = (const float*)d_in[12];
    const float* Wc2    = (const float*)d_in[13];
    const float* bc2    = (const float*)d_in[14];
    const int*   srcv   = (const int*)d_in[15];
    const int*   dstv   = (const int*)d_in[16];
    int E = in_sizes[15];
    float* outp = (float*)d_out;

    char* w = (char*)d_ws;
    size_t off = 0;
    auto alloc = [&](size_t bytes) -> void* {
        void* p = w + off;
        off += (bytes + 255) & ~(size_t)255;
        return p;
    };
    bf16_t* X    = (bf16_t*)alloc((size_t)MPAD * 2048 * sizeof(bf16_t));
    bf16_t* W1t  = (bf16_t*)alloc((size_t)1024 * 2048 * sizeof(bf16_t));
    bf16_t* W2t  = (bf16_t*)alloc((size_t)512 * 256 * sizeof(bf16_t));
    bf16_t* H1   = (bf16_t*)alloc((size_t)MPAD * 1024 * sizeof(bf16_t));
    bf16_t* out1 = (bf16_t*)alloc((size_t)MPAD * 256 * sizeof(bf16_t));
    bf16_t* H2   = (bf16_t*)alloc((size_t)MPAD * 512 * sizeof(bf16_t));
    float*  out2 = (float*)alloc((size_t)MPAD * 128 * sizeof(float));
    // es1/ed1/es2/ed2 contiguous (each 133120 B, 256-aligned): zeroed as one region in setup
    float*  es1  = (float*)alloc((size_t)MPAD * 4 * sizeof(float));
    float*  ed1  = (float*)alloc((size_t)MPAD * 4 * sizeof(float));
    float*  es2  = (float*)alloc((size_t)MPAD * 4 * sizeof(float));
    float*  ed2  = (float*)alloc((size_t)MPAD * 4 * sizeof(float));
    int*  indptr = (int*)alloc(258 * sizeof(int));
    int*  eidx   = (int*)alloc((size_t)E * sizeof(int));

    setup_kernel<<<6543, 256, 0, stream>>>(W1, W1t, W2, W2t, fmap, X, dstv, E,
                                           indptr, eidx, es1, out1);
    // layer 1 (esed fused into gemm epilogue)
    gemm_kernel<<<dim3(1024 / 128, MPAD / 128), 128, 0, stream>>>(
        X, W1t, H1, a_src1, a_dst1, es1, ed1, 2048, 1024, 256);
    attn_kernel<256><<<dim3(NNODE, NB), 256, 0, stream>>>(H1, es1, ed1, indptr, eidx,
                                                          srcv, b1, nullptr, out1);
    // layer 2
    gemm_kernel<<<dim3(512 / 128, MPAD / 128), 128, 0, stream>>>(
        out1, W2t, H2, a_src2, a_dst2, es2, ed2, 256, 512, 128);
    attn_kernel<128><<<dim3(NNODE, NB), 256, 0, stream>>>(H2, es2, ed2, indptr, eidx,
                                                          srcv, b2, out2, nullptr);
    // head
    head_kernel<<<NB, 256, 0, stream>>>(out2, Wp, bp, Wc1, bc1, Wc2, bc2, outp);

    (void)n_in; (void)out_size; (void)ws_size;
}